// Round 1
// baseline (426.342 us; speedup 1.0000x reference)
//
#include <hip/hip_runtime.h>

namespace {

constexpr int WS  = 11;
constexpr int RAD = 5;
constexpr int OT  = 32;            // output tile (square)
constexpr int IT  = OT + 2 * RAD;  // 42 input tile with halo
constexpr float SSIM_C1 = 0.01f * 0.01f;
constexpr float SSIM_C2 = 0.03f * 0.03f;

// gaussian(sigma=1.5, ws=11), normalized; matches np.float32 pipeline to ~1e-7
__device__ __constant__ float GW[WS] = {
    0.00102838f, 0.00759876f, 0.03600077f, 0.10936069f, 0.21300553f,
    0.26601172f, 0.21300553f, 0.10936069f, 0.03600077f, 0.00759876f,
    0.00102838f};

__global__ void init_out(float* out) { out[0] = 1.0f; }

template <bool POOL>
__global__ __launch_bounds__(256)
void ssim_kernel(const float* __restrict__ X, const float* __restrict__ Y,
                 float* __restrict__ out, float coef,
                 float* __restrict__ PX, float* __restrict__ PY,
                 int H, int W)
{
    __shared__ float sx[IT][IT + 2];   // 42x44, stride 44 -> 2-way max (free)
    __shared__ float sy[IT][IT + 2];
    __shared__ float hx [IT][OT + 1];  // stride 33 -> 2-way max (free)
    __shared__ float hy [IT][OT + 1];
    __shared__ float hxx[IT][OT + 1];
    __shared__ float hyy[IT][OT + 1];
    __shared__ float hxy[IT][OT + 1];
    __shared__ float red[4];

    const int tid = threadIdx.x;
    const int n  = blockIdx.z;
    const int by = blockIdx.y * OT;
    const int bx = blockIdx.x * OT;
    const size_t plane = (size_t)H * W;
    const float* Xn = X + (size_t)n * plane;
    const float* Yn = Y + (size_t)n * plane;

    // ---- stage input tile (zero-padded at image borders) ----
    for (int idx = tid; idx < IT * IT; idx += 256) {
        int r = idx / IT, c = idx - r * IT;
        int gr = by + r - RAD, gc = bx + c - RAD;
        float xv = 0.f, yv = 0.f;
        if ((unsigned)gr < (unsigned)H && (unsigned)gc < (unsigned)W) {
            size_t o = (size_t)gr * W + gc;
            xv = Xn[o]; yv = Yn[o];
        }
        sx[r][c] = xv; sy[r][c] = yv;
    }
    __syncthreads();

    // ---- fused 2x2 avg-pool for the next scale (reads in-tile interior only) ----
    if (POOL) {
        int r = tid >> 4, c = tid & 15;        // 16x16 pooled tile, 1 px/thread
        int sr = RAD + 2 * r, sc = RAD + 2 * c;
        float px = 0.25f * (sx[sr][sc] + sx[sr][sc + 1] + sx[sr + 1][sc] + sx[sr + 1][sc + 1]);
        float py = 0.25f * (sy[sr][sc] + sy[sr][sc + 1] + sy[sr + 1][sc] + sy[sr + 1][sc + 1]);
        int Wp = W >> 1;
        size_t po = (size_t)n * (size_t)(H >> 1) * Wp
                  + (size_t)((by >> 1) + r) * Wp + ((bx >> 1) + c);
        PX[po] = px; PY[po] = py;
    }

    // ---- horizontal pass: 5 blurred quantities into LDS ----
    for (int idx = tid; idx < IT * OT; idx += 256) {
        int r = idx >> 5, c = idx & 31;
        float ax = 0.f, ay = 0.f, axx = 0.f, ayy = 0.f, axy = 0.f;
        #pragma unroll
        for (int k = 0; k < WS; ++k) {
            float w = GW[k];
            float xv = sx[r][c + k], yv = sy[r][c + k];
            ax  += w * xv;       ay  += w * yv;
            axx += w * xv * xv;  ayy += w * yv * yv;  axy += w * xv * yv;
        }
        hx[r][c] = ax; hy[r][c] = ay;
        hxx[r][c] = axx; hyy[r][c] = ayy; hxy[r][c] = axy;
    }
    __syncthreads();

    // ---- vertical pass + SSIM map + local accumulate ----
    float acc = 0.f;
    #pragma unroll
    for (int q = 0; q < (OT * OT) / 256; ++q) {
        int idx = tid + q * 256;
        int r = idx >> 5, c = idx & 31;
        float mu1 = 0.f, mu2 = 0.f, vxx = 0.f, vyy = 0.f, vxy = 0.f;
        #pragma unroll
        for (int k = 0; k < WS; ++k) {
            float w = GW[k];
            mu1 += w * hx [r + k][c];  mu2 += w * hy [r + k][c];
            vxx += w * hxx[r + k][c];  vyy += w * hyy[r + k][c];
            vxy += w * hxy[r + k][c];
        }
        float mu1s = mu1 * mu1, mu2s = mu2 * mu2, mu12 = mu1 * mu2;
        float s1 = vxx - mu1s, s2 = vyy - mu2s, s12 = vxy - mu12;
        float num = (2.f * mu12 + SSIM_C1) * (2.f * s12 + SSIM_C2);
        float den = (mu1s + mu2s + SSIM_C1) * (s1 + s2 + SSIM_C2);
        acc += num / den;
    }

    // ---- block reduction: wave shuffle then cross-wave via LDS ----
    #pragma unroll
    for (int off = 32; off > 0; off >>= 1)
        acc += __shfl_down(acc, off, 64);
    if ((tid & 63) == 0) red[tid >> 6] = acc;
    __syncthreads();
    if (tid == 0) {
        float s = red[0] + red[1] + red[2] + red[3];
        atomicAdd(out, -coef * s);
    }
}

} // namespace

extern "C" void kernel_launch(void* const* d_in, const int* in_sizes, int n_in,
                              void* d_out, int out_size, void* d_ws, size_t ws_size,
                              hipStream_t stream)
{
    const float* pred = (const float*)d_in[0];
    const float* targ = (const float*)d_in[1];
    float* out = (float*)d_out;

    const int N = 64;
    float* p1 = (float*)d_ws;                        // 64*256*256 fp32
    float* t1 = p1 + (size_t)N * 256 * 256;
    float* p2 = t1 + (size_t)N * 256 * 256;          // 64*128*128 fp32
    float* t2 = p2 + (size_t)N * 128 * 128;

    hipLaunchKernelGGL(init_out, dim3(1), dim3(1), 0, stream, out);

    const dim3 blk(256);
    hipLaunchKernelGGL((ssim_kernel<true>), dim3(512 / OT, 512 / OT, N), blk, 0, stream,
                       pred, targ, out, 0.5f / (N * 512.f * 512.f), p1, t1, 512, 512);
    hipLaunchKernelGGL((ssim_kernel<true>), dim3(256 / OT, 256 / OT, N), blk, 0, stream,
                       p1, t1, out, 0.3f / (N * 256.f * 256.f), p2, t2, 256, 256);
    hipLaunchKernelGGL((ssim_kernel<false>), dim3(128 / OT, 128 / OT, N), blk, 0, stream,
                       p2, t2, out, 0.2f / (N * 128.f * 128.f), nullptr, nullptr, 128, 128);
}